// Round 1
// baseline (2563.205 us; speedup 1.0000x reference)
//
#include <hip/hip_runtime.h>

#define N_NODES 100000
#define DIM 8

// out = -x  (vectorized float4; fully overwrites d_out each call)
__global__ void init_neg_kernel(const float* __restrict__ x,
                                float* __restrict__ out, int n4) {
    int i = blockIdx.x * blockDim.x + threadIdx.x;
    if (i < n4) {
        float4 v = reinterpret_cast<const float4*>(x)[i];
        float4 o;
        o.x = -v.x; o.y = -v.y; o.z = -v.z; o.w = -v.w;
        reinterpret_cast<float4*>(out)[i] = o;
    }
}

// one thread per edge: msg = (x[row] - x[col]) * w, atomically added at col
__global__ void edge_scatter_kernel(const float* __restrict__ x,
                                    const int* __restrict__ row,
                                    const int* __restrict__ col,
                                    const float* __restrict__ w,
                                    float* __restrict__ out, int nE) {
    int e = blockIdx.x * blockDim.x + threadIdx.x;
    if (e >= nE) return;

    int r = row[e];
    int c = col[e];
    float we = w[e];

    const float4* xr = reinterpret_cast<const float4*>(x + (size_t)r * DIM);
    const float4* xc = reinterpret_cast<const float4*>(x + (size_t)c * DIM);
    float4 a0 = xr[0], a1 = xr[1];
    float4 b0 = xc[0], b1 = xc[1];

    float* o = out + (size_t)c * DIM;
    atomicAdd(o + 0, (a0.x - b0.x) * we);
    atomicAdd(o + 1, (a0.y - b0.y) * we);
    atomicAdd(o + 2, (a0.z - b0.z) * we);
    atomicAdd(o + 3, (a0.w - b0.w) * we);
    atomicAdd(o + 4, (a1.x - b1.x) * we);
    atomicAdd(o + 5, (a1.y - b1.y) * we);
    atomicAdd(o + 6, (a1.z - b1.z) * we);
    atomicAdd(o + 7, (a1.w - b1.w) * we);
}

extern "C" void kernel_launch(void* const* d_in, const int* in_sizes, int n_in,
                              void* d_out, int out_size, void* d_ws, size_t ws_size,
                              hipStream_t stream) {
    const float* x   = (const float*)d_in[0];   // [N, 8] f32
    const int*   row = (const int*)d_in[1];     // [E] i32
    const int*   col = (const int*)d_in[2];     // [E] i32
    const float* w   = (const float*)d_in[3];   // [E] f32
    float* out = (float*)d_out;                 // [N, 8] f32

    int nE = in_sizes[1];
    int n4 = out_size / 4;  // 800000 floats -> 200000 float4

    init_neg_kernel<<<(n4 + 255) / 256, 256, 0, stream>>>(x, out, n4);
    edge_scatter_kernel<<<(nE + 255) / 256, 256, 0, stream>>>(x, row, col, w, out, nE);
}

// Round 2
// 452.019 us; speedup vs baseline: 5.6706x; 5.6706x over previous
//
#include <hip/hip_runtime.h>

#define N_NODES 100000
#define DIM 8
#define NB 128                 // nodes per bucket
#define BSHIFT 7               // log2(NB)
#define NBUCKETS ((N_NODES + NB - 1) / NB)   // 782
#define G1 512                 // hist/scatter blocks

// ---------------- fallback (round-1 atomic path) ----------------
__global__ void init_neg_kernel(const float* __restrict__ x,
                                float* __restrict__ out, int n4) {
    int i = blockIdx.x * blockDim.x + threadIdx.x;
    if (i < n4) {
        float4 v = reinterpret_cast<const float4*>(x)[i];
        float4 o; o.x = -v.x; o.y = -v.y; o.z = -v.z; o.w = -v.w;
        reinterpret_cast<float4*>(out)[i] = o;
    }
}

__global__ void edge_scatter_atomic(const float* __restrict__ x,
                                    const int* __restrict__ row,
                                    const int* __restrict__ col,
                                    const float* __restrict__ w,
                                    float* __restrict__ out, int nE) {
    int e = blockIdx.x * blockDim.x + threadIdx.x;
    if (e >= nE) return;
    int r = row[e], c = col[e];
    float we = w[e];
    const float4* xr = reinterpret_cast<const float4*>(x + (size_t)r * DIM);
    const float4* xc = reinterpret_cast<const float4*>(x + (size_t)c * DIM);
    float4 a0 = xr[0], a1 = xr[1], b0 = xc[0], b1 = xc[1];
    float* o = out + (size_t)c * DIM;
    atomicAdd(o + 0, (a0.x - b0.x) * we); atomicAdd(o + 1, (a0.y - b0.y) * we);
    atomicAdd(o + 2, (a0.z - b0.z) * we); atomicAdd(o + 3, (a0.w - b0.w) * we);
    atomicAdd(o + 4, (a1.x - b1.x) * we); atomicAdd(o + 5, (a1.y - b1.y) * we);
    atomicAdd(o + 6, (a1.z - b1.z) * we); atomicAdd(o + 7, (a1.w - b1.w) * we);
}

// ---------------- sorted pipeline ----------------

// Pass 1: per-block LDS histogram of col buckets
__global__ __launch_bounds__(256) void hist_kernel(const int* __restrict__ col,
                                                   int nE, int espan,
                                                   unsigned* __restrict__ blockHist) {
    __shared__ unsigned hist[NBUCKETS];
    for (int i = threadIdx.x; i < NBUCKETS; i += 256) hist[i] = 0;
    __syncthreads();
    int e0 = blockIdx.x * espan;
    int e1 = min(e0 + espan, nE);
    for (int e = e0 + threadIdx.x; e < e1; e += 256)
        atomicAdd(&hist[((unsigned)col[e]) >> BSHIFT], 1u);
    __syncthreads();
    for (int b = threadIdx.x; b < NBUCKETS; b += 256)
        blockHist[(size_t)b * G1 + blockIdx.x] = hist[b];
}

// Pass 2a: per-bucket totals
__global__ __launch_bounds__(256) void bucket_total_kernel(const unsigned* __restrict__ blockHist,
                                                           unsigned* __restrict__ bucketTotal) {
    __shared__ unsigned sc[256];
    int b = blockIdx.x;
    unsigned s = 0;
    for (int i = threadIdx.x; i < G1; i += 256) s += blockHist[(size_t)b * G1 + i];
    sc[threadIdx.x] = s; __syncthreads();
    for (int off = 128; off > 0; off >>= 1) {
        if (threadIdx.x < off) sc[threadIdx.x] += sc[threadIdx.x + off];
        __syncthreads();
    }
    if (threadIdx.x == 0) bucketTotal[b] = sc[0];
}

// Pass 2b: exclusive scan over bucket totals (single block, 1024 threads >= 782)
__global__ __launch_bounds__(1024) void bucket_scan_kernel(const unsigned* __restrict__ bucketTotal,
                                                           unsigned* __restrict__ bucketStart) {
    __shared__ unsigned sc[1024];
    int t = threadIdx.x;
    unsigned v = (t < NBUCKETS) ? bucketTotal[t] : 0u;
    sc[t] = v; __syncthreads();
    for (int off = 1; off < 1024; off <<= 1) {
        unsigned u = (t >= off) ? sc[t - off] : 0u;
        __syncthreads();
        sc[t] += u; __syncthreads();
    }
    if (t < NBUCKETS) bucketStart[t] = sc[t] - v;          // exclusive
    if (t == NBUCKETS - 1) bucketStart[NBUCKETS] = sc[t];  // total
}

// Pass 2c: per-bucket exclusive scan of the G1 block entries (+bucket base)
__global__ __launch_bounds__(256) void block_offs_kernel(const unsigned* __restrict__ blockHist,
                                                         const unsigned* __restrict__ bucketStart,
                                                         unsigned* __restrict__ blockOffs) {
    __shared__ unsigned sc[256];
    int b = blockIdx.x, t = threadIdx.x;
    unsigned v0 = blockHist[(size_t)b * G1 + 2 * t];
    unsigned v1 = blockHist[(size_t)b * G1 + 2 * t + 1];
    unsigned s = v0 + v1;
    sc[t] = s; __syncthreads();
    for (int off = 1; off < 256; off <<= 1) {
        unsigned u = (t >= off) ? sc[t - off] : 0u;
        __syncthreads();
        sc[t] += u; __syncthreads();
    }
    unsigned ex = sc[t] - s + bucketStart[b];
    blockOffs[(size_t)b * G1 + 2 * t]     = ex;
    blockOffs[(size_t)b * G1 + 2 * t + 1] = ex + v0;
}

// Pass 3: scatter packed payloads into bucket-sorted order
__global__ __launch_bounds__(256) void scatter_kernel(const int* __restrict__ row,
                                                      const int* __restrict__ col,
                                                      const float* __restrict__ w,
                                                      int nE, int espan,
                                                      const unsigned* __restrict__ blockOffs,
                                                      uint2* __restrict__ payload) {
    __shared__ unsigned cursor[NBUCKETS];
    for (int b = threadIdx.x; b < NBUCKETS; b += 256)
        cursor[b] = blockOffs[(size_t)b * G1 + blockIdx.x];
    __syncthreads();
    int e0 = blockIdx.x * espan;
    int e1 = min(e0 + espan, nE);
    for (int e = e0 + threadIdx.x; e < e1; e += 256) {
        unsigned c = (unsigned)col[e];
        unsigned b = c >> BSHIFT;
        unsigned pos = atomicAdd(&cursor[b], 1u);
        payload[pos] = make_uint2(((unsigned)row[e] << BSHIFT) | (c & (NB - 1)),
                                  __float_as_uint(w[e]));
    }
}

// Pass 4: per-bucket gather + LDS accumulate, out = acc - x
__global__ __launch_bounds__(256) void gather_kernel(const float* __restrict__ x,
                                                     const uint2* __restrict__ payload,
                                                     const unsigned* __restrict__ bucketStart,
                                                     float* __restrict__ out) {
    __shared__ float acc[NB * DIM];   // 4 KB
    __shared__ float xl[NB * DIM];    // 4 KB
    int b = blockIdx.x, t = threadIdx.x;
    int nodeBase = b * NB;
    for (int i = t; i < NB * DIM; i += 256) {
        int g = nodeBase * DIM + i;
        xl[i] = (g < N_NODES * DIM) ? x[g] : 0.f;
        acc[i] = 0.f;
    }
    __syncthreads();
    int e0 = (int)bucketStart[b], e1 = (int)bucketStart[b + 1];
    int d = t & 7, sub = t >> 3;      // 32 edges per block-iteration
    for (int e = e0 + sub; e < e1; e += 32) {
        uint2 p = payload[e];
        int cl = (int)(p.x & (NB - 1));
        int r  = (int)(p.x >> BSHIFT);
        float wv = __uint_as_float(p.y);
        float diff = x[(size_t)r * DIM + d] - xl[cl * DIM + d];
        atomicAdd(&acc[cl * DIM + d], diff * wv);   // LDS atomic
    }
    __syncthreads();
    for (int i = t; i < NB * DIM; i += 256) {
        int node = nodeBase + (i >> 3);
        if (node < N_NODES)
            out[(size_t)nodeBase * DIM + i] = acc[i] - xl[i];
    }
}

extern "C" void kernel_launch(void* const* d_in, const int* in_sizes, int n_in,
                              void* d_out, int out_size, void* d_ws, size_t ws_size,
                              hipStream_t stream) {
    const float* x   = (const float*)d_in[0];
    const int*   row = (const int*)d_in[1];
    const int*   col = (const int*)d_in[2];
    const float* w   = (const float*)d_in[3];
    float* out = (float*)d_out;
    int nE = in_sizes[1];

    size_t need = (size_t)nE * sizeof(uint2)
                + (size_t)NBUCKETS * G1 * 4 * 2
                + (size_t)NBUCKETS * 4
                + (size_t)(NBUCKETS + 1) * 4 + 256;

    if (ws_size < need) {
        // fallback: atomic path
        int n4 = out_size / 4;
        init_neg_kernel<<<(n4 + 255) / 256, 256, 0, stream>>>(x, out, n4);
        edge_scatter_atomic<<<(nE + 255) / 256, 256, 0, stream>>>(x, row, col, w, out, nE);
        return;
    }

    char* p = (char*)d_ws;
    uint2*    payload     = (uint2*)p;    p += (size_t)nE * sizeof(uint2);
    unsigned* blockHist   = (unsigned*)p; p += (size_t)NBUCKETS * G1 * 4;
    unsigned* blockOffs   = (unsigned*)p; p += (size_t)NBUCKETS * G1 * 4;
    unsigned* bucketTotal = (unsigned*)p; p += (size_t)NBUCKETS * 4;
    unsigned* bucketStart = (unsigned*)p;

    int espan = (nE + G1 - 1) / G1;

    hist_kernel<<<G1, 256, 0, stream>>>(col, nE, espan, blockHist);
    bucket_total_kernel<<<NBUCKETS, 256, 0, stream>>>(blockHist, bucketTotal);
    bucket_scan_kernel<<<1, 1024, 0, stream>>>(bucketTotal, bucketStart);
    block_offs_kernel<<<NBUCKETS, 256, 0, stream>>>(blockHist, bucketStart, blockOffs);
    scatter_kernel<<<G1, 256, 0, stream>>>(row, col, w, nE, espan, blockOffs, payload);
    gather_kernel<<<NBUCKETS, 256, 0, stream>>>(x, payload, bucketStart, out);
}

// Round 3
// 399.322 us; speedup vs baseline: 6.4189x; 1.1320x over previous
//
#include <hip/hip_runtime.h>

#define N_NODES 100000
#define DIM 8
#define NB 128                 // nodes per bucket
#define BSHIFT 7               // log2(NB)
#define NBUCKETS ((N_NODES + NB - 1) / NB)   // 782
#define G1 512                 // hist/scatter blocks
#define CHUNK 2048             // edges per gather block
#define MAXSLOTS 8             // partial tiles per bucket

// ---------------- fallback (round-1 atomic path) ----------------
__global__ void init_neg_kernel(const float* __restrict__ x,
                                float* __restrict__ out, int n4) {
    int i = blockIdx.x * blockDim.x + threadIdx.x;
    if (i < n4) {
        float4 v = reinterpret_cast<const float4*>(x)[i];
        float4 o; o.x = -v.x; o.y = -v.y; o.z = -v.z; o.w = -v.w;
        reinterpret_cast<float4*>(out)[i] = o;
    }
}

__global__ void edge_scatter_atomic(const float* __restrict__ x,
                                    const int* __restrict__ row,
                                    const int* __restrict__ col,
                                    const float* __restrict__ w,
                                    float* __restrict__ out, int nE) {
    int e = blockIdx.x * blockDim.x + threadIdx.x;
    if (e >= nE) return;
    int r = row[e], c = col[e];
    float we = w[e];
    const float4* xr = reinterpret_cast<const float4*>(x + (size_t)r * DIM);
    const float4* xc = reinterpret_cast<const float4*>(x + (size_t)c * DIM);
    float4 a0 = xr[0], a1 = xr[1], b0 = xc[0], b1 = xc[1];
    float* o = out + (size_t)c * DIM;
    atomicAdd(o + 0, (a0.x - b0.x) * we); atomicAdd(o + 1, (a0.y - b0.y) * we);
    atomicAdd(o + 2, (a0.z - b0.z) * we); atomicAdd(o + 3, (a0.w - b0.w) * we);
    atomicAdd(o + 4, (a1.x - b1.x) * we); atomicAdd(o + 5, (a1.y - b1.y) * we);
    atomicAdd(o + 6, (a1.z - b1.z) * we); atomicAdd(o + 7, (a1.w - b1.w) * we);
}

// ---------------- sorted pipeline ----------------

// Pass 1: per-block LDS histogram of col buckets
__global__ __launch_bounds__(256) void hist_kernel(const int* __restrict__ col,
                                                   int nE, int espan,
                                                   unsigned* __restrict__ blockHist) {
    __shared__ unsigned hist[NBUCKETS];
    for (int i = threadIdx.x; i < NBUCKETS; i += 256) hist[i] = 0;
    __syncthreads();
    int e0 = blockIdx.x * espan;
    int e1 = min(e0 + espan, nE);
    for (int e = e0 + threadIdx.x; e < e1; e += 256)
        atomicAdd(&hist[((unsigned)col[e]) >> BSHIFT], 1u);
    __syncthreads();
    for (int b = threadIdx.x; b < NBUCKETS; b += 256)
        blockHist[(size_t)b * G1 + blockIdx.x] = hist[b];
}

// Pass 2a: per-bucket totals
__global__ __launch_bounds__(256) void bucket_total_kernel(const unsigned* __restrict__ blockHist,
                                                           unsigned* __restrict__ bucketTotal) {
    __shared__ unsigned sc[256];
    int b = blockIdx.x;
    unsigned s = 0;
    for (int i = threadIdx.x; i < G1; i += 256) s += blockHist[(size_t)b * G1 + i];
    sc[threadIdx.x] = s; __syncthreads();
    for (int off = 128; off > 0; off >>= 1) {
        if (threadIdx.x < off) sc[threadIdx.x] += sc[threadIdx.x + off];
        __syncthreads();
    }
    if (threadIdx.x == 0) bucketTotal[b] = sc[0];
}

// Pass 2b: exclusive scan over bucket totals (single block, 1024 threads >= 782)
__global__ __launch_bounds__(1024) void bucket_scan_kernel(const unsigned* __restrict__ bucketTotal,
                                                           unsigned* __restrict__ bucketStart) {
    __shared__ unsigned sc[1024];
    int t = threadIdx.x;
    unsigned v = (t < NBUCKETS) ? bucketTotal[t] : 0u;
    sc[t] = v; __syncthreads();
    for (int off = 1; off < 1024; off <<= 1) {
        unsigned u = (t >= off) ? sc[t - off] : 0u;
        __syncthreads();
        sc[t] += u; __syncthreads();
    }
    if (t < NBUCKETS) bucketStart[t] = sc[t] - v;          // exclusive
    if (t == NBUCKETS - 1) bucketStart[NBUCKETS] = sc[t];  // total
}

// Pass 2c: per-bucket exclusive scan of the G1 block entries (+bucket base)
__global__ __launch_bounds__(256) void block_offs_kernel(const unsigned* __restrict__ blockHist,
                                                         const unsigned* __restrict__ bucketStart,
                                                         unsigned* __restrict__ blockOffs) {
    __shared__ unsigned sc[256];
    int b = blockIdx.x, t = threadIdx.x;
    unsigned v0 = blockHist[(size_t)b * G1 + 2 * t];
    unsigned v1 = blockHist[(size_t)b * G1 + 2 * t + 1];
    unsigned s = v0 + v1;
    sc[t] = s; __syncthreads();
    for (int off = 1; off < 256; off <<= 1) {
        unsigned u = (t >= off) ? sc[t - off] : 0u;
        __syncthreads();
        sc[t] += u; __syncthreads();
    }
    unsigned ex = sc[t] - s + bucketStart[b];
    blockOffs[(size_t)b * G1 + 2 * t]     = ex;
    blockOffs[(size_t)b * G1 + 2 * t + 1] = ex + v0;
}

// Pass 3: scatter packed payloads into bucket-sorted order
__global__ __launch_bounds__(256) void scatter_kernel(const int* __restrict__ row,
                                                      const int* __restrict__ col,
                                                      const float* __restrict__ w,
                                                      int nE, int espan,
                                                      const unsigned* __restrict__ blockOffs,
                                                      uint2* __restrict__ payload) {
    __shared__ unsigned cursor[NBUCKETS];
    for (int b = threadIdx.x; b < NBUCKETS; b += 256)
        cursor[b] = blockOffs[(size_t)b * G1 + blockIdx.x];
    __syncthreads();
    int e0 = blockIdx.x * espan;
    int e1 = min(e0 + espan, nE);
    for (int e = e0 + threadIdx.x; e < e1; e += 256) {
        unsigned c = (unsigned)col[e];
        unsigned b = c >> BSHIFT;
        unsigned pos = atomicAdd(&cursor[b], 1u);
        payload[pos] = make_uint2(((unsigned)row[e] << BSHIFT) | (c & (NB - 1)),
                                  __float_as_uint(w[e]));
    }
}

// Pass 4 (NEW): chunked gather — one block per 2048-edge chunk of the sorted
// payload; accumulate per-bucket segments into an LDS tile; flush partial
// tiles (coalesced) to ws, tagged via a per-bucket slot counter.
__global__ __launch_bounds__(256) void gather_chunk_kernel(
        const float* __restrict__ x,
        const uint2* __restrict__ payload,
        const unsigned* __restrict__ bucketStart,   // NBUCKETS+1
        unsigned* __restrict__ slotCnt,             // NBUCKETS, zeroed per call
        float* __restrict__ partials,               // NBUCKETS*MAXSLOTS*NB*DIM
        float* __restrict__ out,                    // pre-inited to -x (overflow sink)
        int nE) {
    __shared__ float acc[NB * DIM];   // 4 KB
    __shared__ int sh_b;
    __shared__ unsigned sh_slot;
    int t = threadIdx.x;
    int e0 = blockIdx.x * CHUNK;
    int e1 = min(e0 + CHUNK, nE);
    if (e0 >= nE) return;

    if (t == 0) {
        int lo = 0, hi = NBUCKETS;   // bucketStart[lo] <= e0 < bucketStart[hi]
        while (hi - lo > 1) {
            int mid = (lo + hi) >> 1;
            if ((int)bucketStart[mid] <= e0) lo = mid; else hi = mid;
        }
        sh_b = lo;
    }
    __syncthreads();
    int b = sh_b;
    int e = e0;
    int d = t & 7, sub = t >> 3;

    while (e < e1) {
        int segEnd = min(e1, (int)bucketStart[b + 1]);
        if (segEnd <= e) { ++b; continue; }   // empty/finished bucket (uniform)

        for (int i = t; i < NB * DIM; i += 256) acc[i] = 0.f;
        __syncthreads();

        int nodeBase = b * NB;
        // 2-way unrolled edge loop: 32 edges x 8 dims per iteration step
        int ee = e + sub;
        for (; ee + 32 < segEnd; ee += 64) {
            uint2 p0 = payload[ee];
            uint2 p1 = payload[ee + 32];
            int cl0 = (int)(p0.x & (NB - 1)), r0 = (int)(p0.x >> BSHIFT);
            int cl1 = (int)(p1.x & (NB - 1)), r1 = (int)(p1.x >> BSHIFT);
            float xr0 = x[(size_t)r0 * DIM + d];
            float xr1 = x[(size_t)r1 * DIM + d];
            float xc0 = x[(size_t)(nodeBase + cl0) * DIM + d];
            float xc1 = x[(size_t)(nodeBase + cl1) * DIM + d];
            atomicAdd(&acc[cl0 * DIM + d], (xr0 - xc0) * __uint_as_float(p0.y));
            atomicAdd(&acc[cl1 * DIM + d], (xr1 - xc1) * __uint_as_float(p1.y));
        }
        if (ee < segEnd) {
            uint2 p0 = payload[ee];
            int cl0 = (int)(p0.x & (NB - 1)), r0 = (int)(p0.x >> BSHIFT);
            float xr0 = x[(size_t)r0 * DIM + d];
            float xc0 = x[(size_t)(nodeBase + cl0) * DIM + d];
            atomicAdd(&acc[cl0 * DIM + d], (xr0 - xc0) * __uint_as_float(p0.y));
        }
        __syncthreads();

        if (t == 0) sh_slot = atomicAdd(&slotCnt[b], 1u);
        __syncthreads();
        unsigned slot = sh_slot;
        if (slot < MAXSLOTS) {
            float* dst = partials + ((size_t)b * MAXSLOTS + slot) * (NB * DIM);
            for (int i = t; i < NB * DIM; i += 256) dst[i] = acc[i];
        } else {
            // overflow (shouldn't happen): atomic into out
            for (int i = t; i < NB * DIM; i += 256) {
                int node = nodeBase + (i >> 3);
                if (node < N_NODES)
                    atomicAdd(&out[(size_t)nodeBase * DIM + i], acc[i]);
            }
        }
        __syncthreads();
        e = segEnd;
        if ((int)bucketStart[b + 1] <= e) ++b;
    }
}

// Pass 5: per-bucket reduce of partials; out already holds -x (+overflow)
__global__ __launch_bounds__(256) void reduce_kernel(
        const float* __restrict__ partials,
        const unsigned* __restrict__ slotCnt,
        float* __restrict__ out) {
    int b = blockIdx.x, t = threadIdx.x;
    unsigned s = slotCnt[b];
    if (s > MAXSLOTS) s = MAXSLOTS;
    int nodeBase = b * NB;
    for (int i = t; i < NB * DIM; i += 256) {
        int node = nodeBase + (i >> 3);
        if (node >= N_NODES) continue;
        size_t gi = (size_t)nodeBase * DIM + i;
        float a = out[gi];
        for (unsigned k = 0; k < s; ++k)
            a += partials[((size_t)b * MAXSLOTS + k) * (NB * DIM) + i];
        out[gi] = a;
    }
}

// (R2 fallback gather: one block per bucket)
__global__ __launch_bounds__(256) void gather_kernel(const float* __restrict__ x,
                                                     const uint2* __restrict__ payload,
                                                     const unsigned* __restrict__ bucketStart,
                                                     float* __restrict__ out) {
    __shared__ float acc[NB * DIM];
    __shared__ float xl[NB * DIM];
    int b = blockIdx.x, t = threadIdx.x;
    int nodeBase = b * NB;
    for (int i = t; i < NB * DIM; i += 256) {
        int g = nodeBase * DIM + i;
        xl[i] = (g < N_NODES * DIM) ? x[g] : 0.f;
        acc[i] = 0.f;
    }
    __syncthreads();
    int e0 = (int)bucketStart[b], e1 = (int)bucketStart[b + 1];
    int d = t & 7, sub = t >> 3;
    for (int e = e0 + sub; e < e1; e += 32) {
        uint2 p = payload[e];
        int cl = (int)(p.x & (NB - 1));
        int r  = (int)(p.x >> BSHIFT);
        float wv = __uint_as_float(p.y);
        float diff = x[(size_t)r * DIM + d] - xl[cl * DIM + d];
        atomicAdd(&acc[cl * DIM + d], diff * wv);
    }
    __syncthreads();
    for (int i = t; i < NB * DIM; i += 256) {
        int node = nodeBase + (i >> 3);
        if (node < N_NODES)
            out[(size_t)nodeBase * DIM + i] = acc[i] - xl[i];
    }
}

extern "C" void kernel_launch(void* const* d_in, const int* in_sizes, int n_in,
                              void* d_out, int out_size, void* d_ws, size_t ws_size,
                              hipStream_t stream) {
    const float* x   = (const float*)d_in[0];
    const int*   row = (const int*)d_in[1];
    const int*   col = (const int*)d_in[2];
    const float* w   = (const float*)d_in[3];
    float* out = (float*)d_out;
    int nE = in_sizes[1];
    int n4 = out_size / 4;

    size_t off_payload   = 0;
    size_t off_blockHist = off_payload   + (size_t)nE * sizeof(uint2);
    size_t off_blockOffs = off_blockHist + (size_t)NBUCKETS * G1 * 4;
    size_t off_total     = off_blockOffs + (size_t)NBUCKETS * G1 * 4;
    size_t off_start     = off_total     + (size_t)NBUCKETS * 4;
    size_t off_slot      = off_start     + (size_t)(NBUCKETS + 1) * 4;
    size_t off_partials  = off_slot      + (size_t)NBUCKETS * 4;
    size_t need_sorted   = off_partials;
    size_t need_chunked  = off_partials + (size_t)NBUCKETS * MAXSLOTS * NB * DIM * 4;

    if (ws_size < need_sorted) {
        init_neg_kernel<<<(n4 + 255) / 256, 256, 0, stream>>>(x, out, n4);
        edge_scatter_atomic<<<(nE + 255) / 256, 256, 0, stream>>>(x, row, col, w, out, nE);
        return;
    }

    char* p = (char*)d_ws;
    uint2*    payload     = (uint2*)(p + off_payload);
    unsigned* blockHist   = (unsigned*)(p + off_blockHist);
    unsigned* blockOffs   = (unsigned*)(p + off_blockOffs);
    unsigned* bucketTotal = (unsigned*)(p + off_total);
    unsigned* bucketStart = (unsigned*)(p + off_start);
    unsigned* slotCnt     = (unsigned*)(p + off_slot);
    float*    partials    = (float*)(p + off_partials);

    int espan = (nE + G1 - 1) / G1;

    hist_kernel<<<G1, 256, 0, stream>>>(col, nE, espan, blockHist);
    bucket_total_kernel<<<NBUCKETS, 256, 0, stream>>>(blockHist, bucketTotal);
    bucket_scan_kernel<<<1, 1024, 0, stream>>>(bucketTotal, bucketStart);
    block_offs_kernel<<<NBUCKETS, 256, 0, stream>>>(blockHist, bucketStart, blockOffs);
    scatter_kernel<<<G1, 256, 0, stream>>>(row, col, w, nE, espan, blockOffs, payload);

    if (ws_size >= need_chunked) {
        init_neg_kernel<<<(n4 + 255) / 256, 256, 0, stream>>>(x, out, n4);
        hipMemsetAsync(slotCnt, 0, (size_t)NBUCKETS * 4, stream);
        int nChunks = (nE + CHUNK - 1) / CHUNK;
        gather_chunk_kernel<<<nChunks, 256, 0, stream>>>(x, payload, bucketStart,
                                                         slotCnt, partials, out, nE);
        reduce_kernel<<<NBUCKETS, 256, 0, stream>>>(partials, slotCnt, out);
    } else {
        gather_kernel<<<NBUCKETS, 256, 0, stream>>>(x, payload, bucketStart, out);
    }
}

// Round 4
// 205.390 us; speedup vs baseline: 12.4797x; 1.9442x over previous
//
#include <hip/hip_runtime.h>

#define N_NODES 100000
#define DIM 8
#define NB 128                 // nodes per bucket
#define BSHIFT 7               // log2(NB)
#define NBUCKETS ((N_NODES + NB - 1) / NB)   // 782
#define G1 512                 // hist/scatter blocks
#define CHUNK 2048             // edges per gather block (fallback path)
#define MAXSLOTS 8             // partial tiles per bucket (fallback path)

// ---------------- fallback (round-1 atomic path) ----------------
__global__ void init_neg_kernel(const float* __restrict__ x,
                                float* __restrict__ out, int n4) {
    int i = blockIdx.x * blockDim.x + threadIdx.x;
    if (i < n4) {
        float4 v = reinterpret_cast<const float4*>(x)[i];
        float4 o; o.x = -v.x; o.y = -v.y; o.z = -v.z; o.w = -v.w;
        reinterpret_cast<float4*>(out)[i] = o;
    }
}

__global__ void edge_scatter_atomic(const float* __restrict__ x,
                                    const int* __restrict__ row,
                                    const int* __restrict__ col,
                                    const float* __restrict__ w,
                                    float* __restrict__ out, int nE) {
    int e = blockIdx.x * blockDim.x + threadIdx.x;
    if (e >= nE) return;
    int r = row[e], c = col[e];
    float we = w[e];
    const float4* xr = reinterpret_cast<const float4*>(x + (size_t)r * DIM);
    const float4* xc = reinterpret_cast<const float4*>(x + (size_t)c * DIM);
    float4 a0 = xr[0], a1 = xr[1], b0 = xc[0], b1 = xc[1];
    float* o = out + (size_t)c * DIM;
    atomicAdd(o + 0, (a0.x - b0.x) * we); atomicAdd(o + 1, (a0.y - b0.y) * we);
    atomicAdd(o + 2, (a0.z - b0.z) * we); atomicAdd(o + 3, (a0.w - b0.w) * we);
    atomicAdd(o + 4, (a1.x - b1.x) * we); atomicAdd(o + 5, (a1.y - b1.y) * we);
    atomicAdd(o + 6, (a1.z - b1.z) * we); atomicAdd(o + 7, (a1.w - b1.w) * we);
}

// ---------------- sorted pipeline ----------------

// Pass 1: per-block LDS histogram of col buckets
__global__ __launch_bounds__(256) void hist_kernel(const int* __restrict__ col,
                                                   int nE, int espan,
                                                   unsigned* __restrict__ blockHist) {
    __shared__ unsigned hist[NBUCKETS];
    for (int i = threadIdx.x; i < NBUCKETS; i += 256) hist[i] = 0;
    __syncthreads();
    int e0 = blockIdx.x * espan;
    int e1 = min(e0 + espan, nE);
    for (int e = e0 + threadIdx.x; e < e1; e += 256)
        atomicAdd(&hist[((unsigned)col[e]) >> BSHIFT], 1u);
    __syncthreads();
    for (int b = threadIdx.x; b < NBUCKETS; b += 256)
        blockHist[(size_t)b * G1 + blockIdx.x] = hist[b];
}

// Pass 2a: per-bucket totals
__global__ __launch_bounds__(256) void bucket_total_kernel(const unsigned* __restrict__ blockHist,
                                                           unsigned* __restrict__ bucketTotal) {
    __shared__ unsigned sc[256];
    int b = blockIdx.x;
    unsigned s = 0;
    for (int i = threadIdx.x; i < G1; i += 256) s += blockHist[(size_t)b * G1 + i];
    sc[threadIdx.x] = s; __syncthreads();
    for (int off = 128; off > 0; off >>= 1) {
        if (threadIdx.x < off) sc[threadIdx.x] += sc[threadIdx.x + off];
        __syncthreads();
    }
    if (threadIdx.x == 0) bucketTotal[b] = sc[0];
}

// Pass 2b: exclusive scan over bucket totals (single block, 1024 threads >= 782)
__global__ __launch_bounds__(1024) void bucket_scan_kernel(const unsigned* __restrict__ bucketTotal,
                                                           unsigned* __restrict__ bucketStart) {
    __shared__ unsigned sc[1024];
    int t = threadIdx.x;
    unsigned v = (t < NBUCKETS) ? bucketTotal[t] : 0u;
    sc[t] = v; __syncthreads();
    for (int off = 1; off < 1024; off <<= 1) {
        unsigned u = (t >= off) ? sc[t - off] : 0u;
        __syncthreads();
        sc[t] += u; __syncthreads();
    }
    if (t < NBUCKETS) bucketStart[t] = sc[t] - v;          // exclusive
    if (t == NBUCKETS - 1) bucketStart[NBUCKETS] = sc[t];  // total
}

// Pass 2c: per-bucket exclusive scan of the G1 block entries (+bucket base)
__global__ __launch_bounds__(256) void block_offs_kernel(const unsigned* __restrict__ blockHist,
                                                         const unsigned* __restrict__ bucketStart,
                                                         unsigned* __restrict__ blockOffs) {
    __shared__ unsigned sc[256];
    int b = blockIdx.x, t = threadIdx.x;
    unsigned v0 = blockHist[(size_t)b * G1 + 2 * t];
    unsigned v1 = blockHist[(size_t)b * G1 + 2 * t + 1];
    unsigned s = v0 + v1;
    sc[t] = s; __syncthreads();
    for (int off = 1; off < 256; off <<= 1) {
        unsigned u = (t >= off) ? sc[t - off] : 0u;
        __syncthreads();
        sc[t] += u; __syncthreads();
    }
    unsigned ex = sc[t] - s + bucketStart[b];
    blockOffs[(size_t)b * G1 + 2 * t]     = ex;
    blockOffs[(size_t)b * G1 + 2 * t + 1] = ex + v0;
}

// Pass 3: scatter packed payloads into bucket-sorted order
__global__ __launch_bounds__(256) void scatter_kernel(const int* __restrict__ row,
                                                      const int* __restrict__ col,
                                                      const float* __restrict__ w,
                                                      int nE, int espan,
                                                      const unsigned* __restrict__ blockOffs,
                                                      uint2* __restrict__ payload) {
    __shared__ unsigned cursor[NBUCKETS];
    for (int b = threadIdx.x; b < NBUCKETS; b += 256)
        cursor[b] = blockOffs[(size_t)b * G1 + blockIdx.x];
    __syncthreads();
    int e0 = blockIdx.x * espan;
    int e1 = min(e0 + espan, nE);
    for (int e = e0 + threadIdx.x; e < e1; e += 256) {
        unsigned c = (unsigned)col[e];
        unsigned b = c >> BSHIFT;
        unsigned pos = atomicAdd(&cursor[b], 1u);
        payload[pos] = make_uint2(((unsigned)row[e] << BSHIFT) | (c & (NB - 1)),
                                  __float_as_uint(w[e]));
    }
}

// Pass 4 (NEW): in-bucket counting sort by col-low bits -> payloadB (row, w),
// emits per-node CSR offsets nodeStart.
__global__ __launch_bounds__(512) void sort_bucket_kernel(
        const uint2* __restrict__ payloadA,
        const unsigned* __restrict__ bucketStart,
        unsigned* __restrict__ nodeStart,        // >= NBUCKETS*NB + 1 entries
        uint2* __restrict__ payloadB) {
    __shared__ unsigned cnt[NB];
    __shared__ unsigned scanb[NB];
    int b = blockIdx.x, t = threadIdx.x;
    int e0 = (int)bucketStart[b], e1 = (int)bucketStart[b + 1];
    if (t < NB) cnt[t] = 0;
    __syncthreads();
    #pragma unroll 4
    for (int e = e0 + t; e < e1; e += 512)
        atomicAdd(&cnt[payloadA[e].x & (NB - 1)], 1u);
    __syncthreads();
    if (t < NB) scanb[t] = cnt[t];
    __syncthreads();
    for (int off = 1; off < NB; off <<= 1) {
        unsigned v = 0;
        if (t < NB && t >= off) v = scanb[t - off];
        __syncthreads();
        if (t < NB) scanb[t] += v;
        __syncthreads();
    }
    if (t < NB) {
        unsigned base = (unsigned)e0 + (scanb[t] - cnt[t]);  // exclusive
        nodeStart[b * NB + t] = base;
        cnt[t] = base;                                       // cursor
    }
    __syncthreads();
    #pragma unroll 4
    for (int e = e0 + t; e < e1; e += 512) {
        uint2 p = payloadA[e];
        unsigned cl = p.x & (NB - 1);
        unsigned pos = atomicAdd(&cnt[cl], 1u);
        payloadB[pos] = make_uint2(p.x >> BSHIFT, p.y);
    }
}

// Pass 5 (NEW): pure-register CSR gather. thread = (node, dim). No atomics.
__global__ __launch_bounds__(256) void csr_gather_kernel(
        const float* __restrict__ x,
        const uint2* __restrict__ payloadB,
        const unsigned* __restrict__ nodeStart,
        float* __restrict__ out) {
    int gid = blockIdx.x * 256 + threadIdx.x;   // grid sized so gid < N_NODES*DIM
    int n = gid >> 3, d = gid & 7;
    int e = (int)nodeStart[n], eEnd = (int)nodeStart[n + 1];
    float xc = x[(size_t)n * DIM + d];
    float a0 = 0.f, a1 = 0.f;
    for (; e + 4 <= eEnd; e += 4) {
        uint2 p0 = payloadB[e];
        uint2 p1 = payloadB[e + 1];
        uint2 p2 = payloadB[e + 2];
        uint2 p3 = payloadB[e + 3];
        float s0 = x[(size_t)p0.x * DIM + d];
        float s1 = x[(size_t)p1.x * DIM + d];
        float s2 = x[(size_t)p2.x * DIM + d];
        float s3 = x[(size_t)p3.x * DIM + d];
        a0 += (s0 - xc) * __uint_as_float(p0.y);
        a1 += (s1 - xc) * __uint_as_float(p1.y);
        a0 += (s2 - xc) * __uint_as_float(p2.y);
        a1 += (s3 - xc) * __uint_as_float(p3.y);
    }
    for (; e < eEnd; ++e) {
        uint2 p = payloadB[e];
        a0 += (x[(size_t)p.x * DIM + d] - xc) * __uint_as_float(p.y);
    }
    out[(size_t)n * DIM + d] = a0 + a1 - xc;
}

// ---------------- fallback (round-3 chunked path) ----------------
__global__ __launch_bounds__(256) void gather_chunk_kernel(
        const float* __restrict__ x,
        const uint2* __restrict__ payload,
        const unsigned* __restrict__ bucketStart,
        unsigned* __restrict__ slotCnt,
        float* __restrict__ partials,
        float* __restrict__ out,
        int nE) {
    __shared__ float acc[NB * DIM];
    __shared__ int sh_b;
    __shared__ unsigned sh_slot;
    int t = threadIdx.x;
    int e0 = blockIdx.x * CHUNK;
    int e1 = min(e0 + CHUNK, nE);
    if (e0 >= nE) return;
    if (t == 0) {
        int lo = 0, hi = NBUCKETS;
        while (hi - lo > 1) {
            int mid = (lo + hi) >> 1;
            if ((int)bucketStart[mid] <= e0) lo = mid; else hi = mid;
        }
        sh_b = lo;
    }
    __syncthreads();
    int b = sh_b;
    int e = e0;
    int d = t & 7, sub = t >> 3;
    while (e < e1) {
        int segEnd = min(e1, (int)bucketStart[b + 1]);
        if (segEnd <= e) { ++b; continue; }
        for (int i = t; i < NB * DIM; i += 256) acc[i] = 0.f;
        __syncthreads();
        int nodeBase = b * NB;
        int ee = e + sub;
        for (; ee < segEnd; ee += 32) {
            uint2 p0 = payload[ee];
            int cl0 = (int)(p0.x & (NB - 1)), r0 = (int)(p0.x >> BSHIFT);
            float xr0 = x[(size_t)r0 * DIM + d];
            float xc0 = x[(size_t)(nodeBase + cl0) * DIM + d];
            atomicAdd(&acc[cl0 * DIM + d], (xr0 - xc0) * __uint_as_float(p0.y));
        }
        __syncthreads();
        if (t == 0) sh_slot = atomicAdd(&slotCnt[b], 1u);
        __syncthreads();
        unsigned slot = sh_slot;
        if (slot < MAXSLOTS) {
            float* dst = partials + ((size_t)b * MAXSLOTS + slot) * (NB * DIM);
            for (int i = t; i < NB * DIM; i += 256) dst[i] = acc[i];
        } else {
            for (int i = t; i < NB * DIM; i += 256) {
                int node = nodeBase + (i >> 3);
                if (node < N_NODES)
                    atomicAdd(&out[(size_t)nodeBase * DIM + i], acc[i]);
            }
        }
        __syncthreads();
        e = segEnd;
        if ((int)bucketStart[b + 1] <= e) ++b;
    }
}

__global__ __launch_bounds__(256) void reduce_kernel(
        const float* __restrict__ partials,
        const unsigned* __restrict__ slotCnt,
        float* __restrict__ out) {
    int b = blockIdx.x, t = threadIdx.x;
    unsigned s = slotCnt[b];
    if (s > MAXSLOTS) s = MAXSLOTS;
    int nodeBase = b * NB;
    for (int i = t; i < NB * DIM; i += 256) {
        int node = nodeBase + (i >> 3);
        if (node >= N_NODES) continue;
        size_t gi = (size_t)nodeBase * DIM + i;
        float a = out[gi];
        for (unsigned k = 0; k < s; ++k)
            a += partials[((size_t)b * MAXSLOTS + k) * (NB * DIM) + i];
        out[gi] = a;
    }
}

extern "C" void kernel_launch(void* const* d_in, const int* in_sizes, int n_in,
                              void* d_out, int out_size, void* d_ws, size_t ws_size,
                              hipStream_t stream) {
    const float* x   = (const float*)d_in[0];
    const int*   row = (const int*)d_in[1];
    const int*   col = (const int*)d_in[2];
    const float* w   = (const float*)d_in[3];
    float* out = (float*)d_out;
    int nE = in_sizes[1];
    int n4 = out_size / 4;

    // shared prefix layout
    size_t off_payloadA  = 0;
    size_t off_blockHist = off_payloadA  + (size_t)nE * sizeof(uint2);
    size_t off_blockOffs = off_blockHist + (size_t)NBUCKETS * G1 * 4;
    size_t off_total     = off_blockOffs + (size_t)NBUCKETS * G1 * 4;
    size_t off_start     = off_total     + (size_t)NBUCKETS * 4;
    size_t off_branch    = off_start     + (size_t)(NBUCKETS + 1) * 4;
    // CSR branch
    size_t off_nodeStart = off_branch;
    size_t off_payloadB  = off_nodeStart + (size_t)(NBUCKETS * NB + 2) * 4;
    size_t need_csr      = off_payloadB  + (size_t)nE * sizeof(uint2);
    // chunked branch
    size_t off_slot      = off_branch;
    size_t off_partials  = off_slot + (size_t)NBUCKETS * 4;
    size_t need_chunked  = off_partials + (size_t)NBUCKETS * MAXSLOTS * NB * DIM * 4;
    size_t need_sorted   = off_branch;

    if (ws_size < need_sorted) {
        init_neg_kernel<<<(n4 + 255) / 256, 256, 0, stream>>>(x, out, n4);
        edge_scatter_atomic<<<(nE + 255) / 256, 256, 0, stream>>>(x, row, col, w, out, nE);
        return;
    }

    char* p = (char*)d_ws;
    uint2*    payloadA    = (uint2*)(p + off_payloadA);
    unsigned* blockHist   = (unsigned*)(p + off_blockHist);
    unsigned* blockOffs   = (unsigned*)(p + off_blockOffs);
    unsigned* bucketTotal = (unsigned*)(p + off_total);
    unsigned* bucketStart = (unsigned*)(p + off_start);

    int espan = (nE + G1 - 1) / G1;

    hist_kernel<<<G1, 256, 0, stream>>>(col, nE, espan, blockHist);
    bucket_total_kernel<<<NBUCKETS, 256, 0, stream>>>(blockHist, bucketTotal);
    bucket_scan_kernel<<<1, 1024, 0, stream>>>(bucketTotal, bucketStart);
    block_offs_kernel<<<NBUCKETS, 256, 0, stream>>>(blockHist, bucketStart, blockOffs);
    scatter_kernel<<<G1, 256, 0, stream>>>(row, col, w, nE, espan, blockOffs, payloadA);

    if (ws_size >= need_csr) {
        unsigned* nodeStart = (unsigned*)(p + off_nodeStart);
        uint2*    payloadB  = (uint2*)(p + off_payloadB);
        sort_bucket_kernel<<<NBUCKETS, 512, 0, stream>>>(payloadA, bucketStart,
                                                         nodeStart, payloadB);
        csr_gather_kernel<<<(N_NODES * DIM) / 256, 256, 0, stream>>>(x, payloadB,
                                                                     nodeStart, out);
    } else if (ws_size >= need_chunked) {
        unsigned* slotCnt  = (unsigned*)(p + off_slot);
        float*    partials = (float*)(p + off_partials);
        init_neg_kernel<<<(n4 + 255) / 256, 256, 0, stream>>>(x, out, n4);
        hipMemsetAsync(slotCnt, 0, (size_t)NBUCKETS * 4, stream);
        int nChunks = (nE + CHUNK - 1) / CHUNK;
        gather_chunk_kernel<<<nChunks, 256, 0, stream>>>(x, payloadA, bucketStart,
                                                         slotCnt, partials, out, nE);
        reduce_kernel<<<NBUCKETS, 256, 0, stream>>>(partials, slotCnt, out);
    } else {
        // R2 single-block-per-bucket path removed; use atomic fallback
        init_neg_kernel<<<(n4 + 255) / 256, 256, 0, stream>>>(x, out, n4);
        edge_scatter_atomic<<<(nE + 255) / 256, 256, 0, stream>>>(x, row, col, w, out, nE);
    }
}

// Round 5
// 181.166 us; speedup vs baseline: 14.1484x; 1.1337x over previous
//
#include <hip/hip_runtime.h>

#define N_NODES 100000
#define DIM 8
#define NB 128                 // nodes per bucket
#define BSHIFT 7               // log2(NB)
#define NBUCKETS ((N_NODES + NB - 1) / NB)   // 782
#define G1 1024                // hist/scatter blocks
#define ESPAN_MAX 6400         // max edges per scatter block (LDS staging cap)
#define SCT 512                // scatter block threads

// ---------------- fallback (atomic path, tiny ws) ----------------
__global__ void init_neg_kernel(const float* __restrict__ x,
                                float* __restrict__ out, int n4) {
    int i = blockIdx.x * blockDim.x + threadIdx.x;
    if (i < n4) {
        float4 v = reinterpret_cast<const float4*>(x)[i];
        float4 o; o.x = -v.x; o.y = -v.y; o.z = -v.z; o.w = -v.w;
        reinterpret_cast<float4*>(out)[i] = o;
    }
}

__global__ void edge_scatter_atomic(const float* __restrict__ x,
                                    const int* __restrict__ row,
                                    const int* __restrict__ col,
                                    const float* __restrict__ w,
                                    float* __restrict__ out, int nE) {
    int e = blockIdx.x * blockDim.x + threadIdx.x;
    if (e >= nE) return;
    int r = row[e], c = col[e];
    float we = w[e];
    const float4* xr = reinterpret_cast<const float4*>(x + (size_t)r * DIM);
    const float4* xc = reinterpret_cast<const float4*>(x + (size_t)c * DIM);
    float4 a0 = xr[0], a1 = xr[1], b0 = xc[0], b1 = xc[1];
    float* o = out + (size_t)c * DIM;
    atomicAdd(o + 0, (a0.x - b0.x) * we); atomicAdd(o + 1, (a0.y - b0.y) * we);
    atomicAdd(o + 2, (a0.z - b0.z) * we); atomicAdd(o + 3, (a0.w - b0.w) * we);
    atomicAdd(o + 4, (a1.x - b1.x) * we); atomicAdd(o + 5, (a1.y - b1.y) * we);
    atomicAdd(o + 6, (a1.z - b1.z) * we); atomicAdd(o + 7, (a1.w - b1.w) * we);
}

// ---------------- sorted pipeline ----------------
// blockHist / blockOffs layout: [blk][bucket]  (blk*NBUCKETS + b)

// Pass 1: per-block LDS histogram of col buckets
__global__ __launch_bounds__(256) void hist_kernel(const int* __restrict__ col,
                                                   int nE, int espan,
                                                   unsigned* __restrict__ blockHist) {
    __shared__ unsigned hist[NBUCKETS];
    for (int i = threadIdx.x; i < NBUCKETS; i += 256) hist[i] = 0;
    __syncthreads();
    int e0 = blockIdx.x * espan;
    int e1 = min(e0 + espan, nE);
    for (int e = e0 + threadIdx.x; e < e1; e += 256)
        atomicAdd(&hist[((unsigned)col[e]) >> BSHIFT], 1u);
    __syncthreads();
    for (int b = threadIdx.x; b < NBUCKETS; b += 256)
        blockHist[(size_t)blockIdx.x * NBUCKETS + b] = hist[b];
}

// Pass 2a: per-bucket totals (sum over blocks)
__global__ __launch_bounds__(256) void bucket_total_kernel(const unsigned* __restrict__ blockHist,
                                                           unsigned* __restrict__ bucketTotal) {
    __shared__ unsigned sc[256];
    int b = blockIdx.x;
    unsigned s = 0;
    for (int i = threadIdx.x; i < G1; i += 256) s += blockHist[(size_t)i * NBUCKETS + b];
    sc[threadIdx.x] = s; __syncthreads();
    for (int off = 128; off > 0; off >>= 1) {
        if (threadIdx.x < off) sc[threadIdx.x] += sc[threadIdx.x + off];
        __syncthreads();
    }
    if (threadIdx.x == 0) bucketTotal[b] = sc[0];
}

// Pass 2b: exclusive scan over bucket totals (single block, 1024 threads >= 782)
__global__ __launch_bounds__(1024) void bucket_scan_kernel(const unsigned* __restrict__ bucketTotal,
                                                           unsigned* __restrict__ bucketStart) {
    __shared__ unsigned sc[1024];
    int t = threadIdx.x;
    unsigned v = (t < NBUCKETS) ? bucketTotal[t] : 0u;
    sc[t] = v; __syncthreads();
    for (int off = 1; off < 1024; off <<= 1) {
        unsigned u = (t >= off) ? sc[t - off] : 0u;
        __syncthreads();
        sc[t] += u; __syncthreads();
    }
    if (t < NBUCKETS) bucketStart[t] = sc[t] - v;          // exclusive
    if (t == NBUCKETS - 1) bucketStart[NBUCKETS] = sc[t];  // total
}

// Pass 2c: per-bucket exclusive scan over the G1 block entries (+bucket base)
__global__ __launch_bounds__(256) void block_offs_kernel(const unsigned* __restrict__ blockHist,
                                                         const unsigned* __restrict__ bucketStart,
                                                         unsigned* __restrict__ blockOffs) {
    __shared__ unsigned part[256];
    int b = blockIdx.x, t = threadIdx.x;
    const int C = G1 / 256;            // 4 entries per thread
    unsigned vv[C], s = 0;
    #pragma unroll
    for (int j = 0; j < C; ++j) {
        vv[j] = blockHist[(size_t)(t * C + j) * NBUCKETS + b];
        s += vv[j];
    }
    part[t] = s; __syncthreads();
    for (int off = 1; off < 256; off <<= 1) {
        unsigned u = (t >= off) ? part[t - off] : 0u;
        __syncthreads();
        part[t] += u; __syncthreads();
    }
    unsigned base = part[t] - s + bucketStart[b];   // exclusive prefix
    #pragma unroll
    for (int j = 0; j < C; ++j) {
        blockOffs[(size_t)(t * C + j) * NBUCKETS + b] = base;
        base += vv[j];
    }
}

// Pass 3 (NEW): block-local counting sort, then coalesced run-flush to payloadA.
__global__ __launch_bounds__(SCT) void scatter_local_kernel(
        const int* __restrict__ row,
        const int* __restrict__ col,
        const float* __restrict__ w,
        int nE, int espan,
        const unsigned* __restrict__ blockOffs,
        uint2* __restrict__ payload) {
    __shared__ uint2 stage[ESPAN_MAX];           // 51.2 KB
    __shared__ unsigned short sbkt[ESPAN_MAX];   // 12.8 KB
    __shared__ unsigned cnt[NBUCKETS];           // counts -> cursors
    __shared__ unsigned lstart[NBUCKETS];
    __shared__ unsigned gbase[NBUCKETS];
    __shared__ unsigned part[SCT];

    int t = threadIdx.x, blk = blockIdx.x;
    int e0 = blk * espan;
    int e1 = min(e0 + espan, nE);
    int n = e1 - e0;

    for (int i = t; i < NBUCKETS; i += SCT) cnt[i] = 0;
    __syncthreads();

    // pass A: count
    for (int k = t; k < n; k += SCT)
        atomicAdd(&cnt[((unsigned)col[e0 + k]) >> BSHIFT], 1u);
    __syncthreads();

    // local exclusive scan of cnt -> lstart (2 entries per thread, 512 threads)
    unsigned c0 = (2 * t < NBUCKETS) ? cnt[2 * t] : 0u;
    unsigned c1 = (2 * t + 1 < NBUCKETS) ? cnt[2 * t + 1] : 0u;
    part[t] = c0 + c1; __syncthreads();
    for (int off = 1; off < SCT; off <<= 1) {
        unsigned u = (t >= off) ? part[t - off] : 0u;
        __syncthreads();
        part[t] += u; __syncthreads();
    }
    unsigned cbase = part[t] - (c0 + c1);
    if (2 * t < NBUCKETS)     lstart[2 * t] = cbase;
    if (2 * t + 1 < NBUCKETS) lstart[2 * t + 1] = cbase + c0;
    __syncthreads();
    // cursors start at lstart
    for (int i = t; i < NBUCKETS; i += SCT) cnt[i] = lstart[i];
    // load global run bases for this block (contiguous)
    for (int b = t; b < NBUCKETS; b += SCT)
        gbase[b] = blockOffs[(size_t)blk * NBUCKETS + b];
    __syncthreads();

    // pass B: local scatter into LDS staging
    for (int k = t; k < n; k += SCT) {
        unsigned c = (unsigned)col[e0 + k];
        unsigned b = c >> BSHIFT;
        unsigned pos = atomicAdd(&cnt[b], 1u);
        stage[pos] = make_uint2(((unsigned)row[e0 + k] << BSHIFT) | (c & (NB - 1)),
                                __float_as_uint(w[e0 + k]));
        sbkt[pos] = (unsigned short)b;
    }
    __syncthreads();

    // flush: contiguous per-bucket runs -> coalesced global writes
    for (int k = t; k < n; k += SCT) {
        unsigned b = sbkt[k];
        unsigned gpos = gbase[b] + ((unsigned)k - lstart[b]);
        payload[gpos] = stage[k];
    }
}

// Fallback pass 3 for espan > ESPAN_MAX: cursor-atomic scatter
__global__ __launch_bounds__(256) void scatter_simple_kernel(
        const int* __restrict__ row,
        const int* __restrict__ col,
        const float* __restrict__ w,
        int nE, int espan,
        const unsigned* __restrict__ blockOffs,
        uint2* __restrict__ payload) {
    __shared__ unsigned cursor[NBUCKETS];
    for (int b = threadIdx.x; b < NBUCKETS; b += 256)
        cursor[b] = blockOffs[(size_t)blockIdx.x * NBUCKETS + b];
    __syncthreads();
    int e0 = blockIdx.x * espan;
    int e1 = min(e0 + espan, nE);
    for (int e = e0 + threadIdx.x; e < e1; e += 256) {
        unsigned c = (unsigned)col[e];
        unsigned b = c >> BSHIFT;
        unsigned pos = atomicAdd(&cursor[b], 1u);
        payload[pos] = make_uint2(((unsigned)row[e] << BSHIFT) | (c & (NB - 1)),
                                  __float_as_uint(w[e]));
    }
}

// Pass 4: in-bucket counting sort by col-low bits -> payloadB (row, w),
// emits per-node CSR offsets nodeStart.
__global__ __launch_bounds__(512) void sort_bucket_kernel(
        const uint2* __restrict__ payloadA,
        const unsigned* __restrict__ bucketStart,
        unsigned* __restrict__ nodeStart,        // >= NBUCKETS*NB + 1 entries
        uint2* __restrict__ payloadB) {
    __shared__ unsigned cnt[NB];
    __shared__ unsigned scanb[NB];
    int b = blockIdx.x, t = threadIdx.x;
    int e0 = (int)bucketStart[b], e1 = (int)bucketStart[b + 1];
    if (t < NB) cnt[t] = 0;
    __syncthreads();
    #pragma unroll 4
    for (int e = e0 + t; e < e1; e += 512)
        atomicAdd(&cnt[payloadA[e].x & (NB - 1)], 1u);
    __syncthreads();
    if (t < NB) scanb[t] = cnt[t];
    __syncthreads();
    for (int off = 1; off < NB; off <<= 1) {
        unsigned v = 0;
        if (t < NB && t >= off) v = scanb[t - off];
        __syncthreads();
        if (t < NB) scanb[t] += v;
        __syncthreads();
    }
    if (t < NB) {
        unsigned base = (unsigned)e0 + (scanb[t] - cnt[t]);  // exclusive
        nodeStart[b * NB + t] = base;
        cnt[t] = base;                                       // cursor
    }
    __syncthreads();
    #pragma unroll 4
    for (int e = e0 + t; e < e1; e += 512) {
        uint2 p = payloadA[e];
        unsigned cl = p.x & (NB - 1);
        unsigned pos = atomicAdd(&cnt[cl], 1u);
        payloadB[pos] = make_uint2(p.x >> BSHIFT, p.y);
    }
}

// Pass 5: pure-register CSR gather. thread = (node, dim). No atomics.
__global__ __launch_bounds__(256) void csr_gather_kernel(
        const float* __restrict__ x,
        const uint2* __restrict__ payloadB,
        const unsigned* __restrict__ nodeStart,
        float* __restrict__ out) {
    int gid = blockIdx.x * 256 + threadIdx.x;
    int n = gid >> 3, d = gid & 7;
    int e = (int)nodeStart[n], eEnd = (int)nodeStart[n + 1];
    float xc = x[(size_t)n * DIM + d];
    float a0 = 0.f, a1 = 0.f;
    for (; e + 4 <= eEnd; e += 4) {
        uint2 p0 = payloadB[e];
        uint2 p1 = payloadB[e + 1];
        uint2 p2 = payloadB[e + 2];
        uint2 p3 = payloadB[e + 3];
        float s0 = x[(size_t)p0.x * DIM + d];
        float s1 = x[(size_t)p1.x * DIM + d];
        float s2 = x[(size_t)p2.x * DIM + d];
        float s3 = x[(size_t)p3.x * DIM + d];
        a0 += (s0 - xc) * __uint_as_float(p0.y);
        a1 += (s1 - xc) * __uint_as_float(p1.y);
        a0 += (s2 - xc) * __uint_as_float(p2.y);
        a1 += (s3 - xc) * __uint_as_float(p3.y);
    }
    for (; e < eEnd; ++e) {
        uint2 p = payloadB[e];
        a0 += (x[(size_t)p.x * DIM + d] - xc) * __uint_as_float(p.y);
    }
    out[(size_t)n * DIM + d] = a0 + a1 - xc;
}

extern "C" void kernel_launch(void* const* d_in, const int* in_sizes, int n_in,
                              void* d_out, int out_size, void* d_ws, size_t ws_size,
                              hipStream_t stream) {
    const float* x   = (const float*)d_in[0];
    const int*   row = (const int*)d_in[1];
    const int*   col = (const int*)d_in[2];
    const float* w   = (const float*)d_in[3];
    float* out = (float*)d_out;
    int nE = in_sizes[1];
    int n4 = out_size / 4;

    size_t off_payloadA  = 0;
    size_t off_blockHist = off_payloadA  + (size_t)nE * sizeof(uint2);
    size_t off_blockOffs = off_blockHist + (size_t)G1 * NBUCKETS * 4;
    size_t off_total     = off_blockOffs + (size_t)G1 * NBUCKETS * 4;
    size_t off_start     = off_total     + (size_t)NBUCKETS * 4;
    size_t off_nodeStart = off_start     + (size_t)(NBUCKETS + 1) * 4;
    size_t off_payloadB  = off_nodeStart + (size_t)(NBUCKETS * NB + 2) * 4;
    size_t need_csr      = off_payloadB  + (size_t)nE * sizeof(uint2);

    if (ws_size < need_csr) {
        init_neg_kernel<<<(n4 + 255) / 256, 256, 0, stream>>>(x, out, n4);
        edge_scatter_atomic<<<(nE + 255) / 256, 256, 0, stream>>>(x, row, col, w, out, nE);
        return;
    }

    char* p = (char*)d_ws;
    uint2*    payloadA    = (uint2*)(p + off_payloadA);
    unsigned* blockHist   = (unsigned*)(p + off_blockHist);
    unsigned* blockOffs   = (unsigned*)(p + off_blockOffs);
    unsigned* bucketTotal = (unsigned*)(p + off_total);
    unsigned* bucketStart = (unsigned*)(p + off_start);
    unsigned* nodeStart   = (unsigned*)(p + off_nodeStart);
    uint2*    payloadB    = (uint2*)(p + off_payloadB);

    int espan = (nE + G1 - 1) / G1;

    hist_kernel<<<G1, 256, 0, stream>>>(col, nE, espan, blockHist);
    bucket_total_kernel<<<NBUCKETS, 256, 0, stream>>>(blockHist, bucketTotal);
    bucket_scan_kernel<<<1, 1024, 0, stream>>>(bucketTotal, bucketStart);
    block_offs_kernel<<<NBUCKETS, 256, 0, stream>>>(blockHist, bucketStart, blockOffs);

    if (espan <= ESPAN_MAX) {
        scatter_local_kernel<<<G1, SCT, 0, stream>>>(row, col, w, nE, espan,
                                                     blockOffs, payloadA);
    } else {
        scatter_simple_kernel<<<G1, 256, 0, stream>>>(row, col, w, nE, espan,
                                                      blockOffs, payloadA);
    }
    sort_bucket_kernel<<<NBUCKETS, 512, 0, stream>>>(payloadA, bucketStart,
                                                     nodeStart, payloadB);
    csr_gather_kernel<<<(N_NODES * DIM) / 256, 256, 0, stream>>>(x, payloadB,
                                                                 nodeStart, out);
}